// Round 9
// baseline (21746.536 us; speedup 1.0000x reference)
//
#include <hip/hip_runtime.h>

#define T_N 512
#define B_N 32
#define H_N 512
#define G3 1536
#define NBLK 192
#define NT 1024
#define EPS_LN 1e-5f
#define OUT_HID_OFF (T_N * B_N * 1024)
#define COLL_BID 16   // kind0 block: no post-barrier work, hosts collector

// ws layout (floats):
//  [0..192)     arrive flags: 1 uint per block (monotone epoch)
//  [256]        release word
//  [448)        stats ring: 4 slots x (4 kd x 3 g x 32 b x 2) = 4 x 768
//  [3520)       axd ring: 3 slots x [2 d][32 b][1536 j]  (ax(s) in slot s%3)
//  [298432)     ahd ring: 2 slots x [2 d][32 b][1536 j]  (ah(s) in slot s&1)
//  [495040)     y0: [2 d][512 t][32 b][512]  (cstore ph0, plain-read ph1)
#define WS_STATS 448
#define STSLOT   768
#define WS_AXD   (WS_STATS + 4 * STSLOT)
#define DSLOT    (2 * B_N * G3)
#define WS_AHD   (WS_AXD + 3 * DSLOT)
#define WS_Y0    (WS_AHD + 2 * DSLOT)

// LDS (163072 B — proven): wlds 32256, hl 8256 (local h state), sred 256
#define WLDS_F 32256
#define HL_F   8256
#define LDS_BYTES ((WLDS_F + HL_F + 256) * 4)

__device__ __forceinline__ float cload(const float* p) {
  return __hip_atomic_load(p, __ATOMIC_RELAXED, __HIP_MEMORY_SCOPE_AGENT);
}
__device__ __forceinline__ void cstore(float* p, float v) {
  __hip_atomic_store(p, v, __ATOMIC_RELAXED, __HIP_MEMORY_SCOPE_AGENT);
}

// Flag-based grid barrier (r7-proven): per-block arrive flag, collector
// block polls all flags with 192 threads, single release word.
__device__ __forceinline__ void gbar(unsigned* barbase, unsigned& epoch, int bid) {
  epoch++;
  unsigned* arr = barbase;
  unsigned* rel = barbase + 256;
  __builtin_amdgcn_s_waitcnt(0);   // drain my vmem: coherent stores at L3
  __syncthreads();
  const int tid = threadIdx.x;
  if (tid == 0)
    __hip_atomic_store(&arr[bid], epoch, __ATOMIC_RELAXED, __HIP_MEMORY_SCOPE_AGENT);
  if (bid == COLL_BID) {
    if (tid < NBLK) {
      while (__hip_atomic_load(&arr[tid], __ATOMIC_RELAXED, __HIP_MEMORY_SCOPE_AGENT) < epoch)
        __builtin_amdgcn_s_sleep(1);
    }
    __syncthreads();
    if (tid == 0)
      __hip_atomic_store(rel, epoch, __ATOMIC_RELAXED, __HIP_MEMORY_SCOPE_AGENT);
  } else {
    if (tid == 0) {
      while (__hip_atomic_load(rel, __ATOMIC_RELAXED, __HIP_MEMORY_SCOPE_AGENT) < epoch)
        __builtin_amdgcn_s_sleep(1);
    }
  }
  __syncthreads();
}

// 16 FMAs: 2 j-weights (WA,WB) x 2 b-rows (R1,R2), componentwise (c = k&3).
#define FMA16(WA, WB, R1, R2) do { \
  acc[0][0][0]=fmaf((R1).x,(WA).x,acc[0][0][0]); acc[0][0][1]=fmaf((R1).y,(WA).y,acc[0][0][1]); \
  acc[0][0][2]=fmaf((R1).z,(WA).z,acc[0][0][2]); acc[0][0][3]=fmaf((R1).w,(WA).w,acc[0][0][3]); \
  acc[0][1][0]=fmaf((R2).x,(WA).x,acc[0][1][0]); acc[0][1][1]=fmaf((R2).y,(WA).y,acc[0][1][1]); \
  acc[0][1][2]=fmaf((R2).z,(WA).z,acc[0][1][2]); acc[0][1][3]=fmaf((R2).w,(WA).w,acc[0][1][3]); \
  acc[1][0][0]=fmaf((R1).x,(WB).x,acc[1][0][0]); acc[1][0][1]=fmaf((R1).y,(WB).y,acc[1][0][1]); \
  acc[1][0][2]=fmaf((R1).z,(WB).z,acc[1][0][2]); acc[1][0][3]=fmaf((R1).w,(WB).w,acc[1][0][3]); \
  acc[1][1][0]=fmaf((R2).x,(WB).x,acc[1][1][0]); acc[1][1][1]=fmaf((R2).y,(WB).y,acc[1][1][1]); \
  acc[1][1][2]=fmaf((R2).z,(WB).z,acc[1][1][2]); acc[1][1][3]=fmaf((R2).w,(WB).w,acc[1][1][3]); \
} while (0)

__global__ void __launch_bounds__(NT, 1)
lngru14(const float* __restrict__ x, const float* __restrict__ h0,
        const float* __restrict__ Wx, const float* __restrict__ Wh,
        const float* __restrict__ bx, const float* __restrict__ bh,
        const float* __restrict__ gx, const float* __restrict__ bex,
        const float* __restrict__ gh, const float* __restrict__ beh,
        float* __restrict__ out, float* __restrict__ ws)
{
  extern __shared__ __align__(16) float smem[];
  float* wlds = smem;                    // [k4 126][j 64][4]
  float* hl   = smem + WLDS_F;           // [b 16][516]  (kind1: local h state)
  float* sred = smem + WLDS_F + HL_F;    // [b_loc 16][jq 4][2]

  unsigned* barbase = (unsigned*)ws;
  float* stats = ws + WS_STATS;
  float* axd   = ws + WS_AXD;
  float* ahd   = ws + WS_AHD;
  float* y0    = ws + WS_Y0;

  const int tid  = threadIdx.x;
  const int lane = tid & 63;
  const int wv   = tid >> 6;              // 16 waves
  const int bid  = blockIdx.x;
  const int bs   = bid & 1;               // b-half
  const int jt   = (bid >> 1) % 24;       // 64-wide j tile
  const int kd   = (bid >> 1) / 24;       // d*2 + kind
  const int kind = kd & 1;                // 0: ax, 1: ah
  const int d    = kd >> 1;
  const int j0   = jt * 64;
  const int g    = jt >> 3;               // gate of this j-tile
  const int b0   = bs * 16;
  const bool writer = (kind == 1) && (jt == 0);   // y0/out/hT writer

  // GEMM (r3-proven): 4 waves (wv<4); lane = (boct 8)x(jj 8);
  // lane tile 2j x 2b: j in {j0+jq*8+jj, +32}, b in {b0+boct, +8}, full K.
  const bool gw  = (wv < 4);
  const int jq   = wv & 3;
  const int jj   = lane & 7;
  const int boct = lane >> 3;
  const int jla  = jq * 8 + jj;
  const int jlb  = jla + 32;

  unsigned epoch = 0;

  for (int ph = 0; ph < 2; ++ph) {
    const int widx = ph * 2 + d;

    gbar(barbase, epoch, bid);   // phase entry: prior phase's y0/out drained

    // ---- stage weights: k<504 -> LDS, k>=504 -> gw-lane tail regs ----
    const float* wgl = (kind ? Wh : Wx) + (size_t)widx * H_N * G3 + j0;
    for (int kk = 0; kk < 32; ++kk) {
      int k = wv * 32 + kk;
      if (k < 504)
        wlds[(k >> 2) * 256 + lane * 4 + (k & 3)] = wgl[(size_t)k * G3 + lane];
    }
    float4 wt[2][2];
    float  bva = 0.f, bvb = 0.f;
    if (gw) {
      bva = (kind ? bh : bx)[widx * G3 + j0 + jla];
      bvb = (kind ? bh : bx)[widx * G3 + j0 + jlb];
#pragma unroll
      for (int h = 0; h < 2; ++h) {
        wt[0][h].x = wgl[(size_t)(504 + 4*h + 0) * G3 + jla];
        wt[0][h].y = wgl[(size_t)(504 + 4*h + 1) * G3 + jla];
        wt[0][h].z = wgl[(size_t)(504 + 4*h + 2) * G3 + jla];
        wt[0][h].w = wgl[(size_t)(504 + 4*h + 3) * G3 + jla];
        wt[1][h].x = wgl[(size_t)(504 + 4*h + 0) * G3 + jlb];
        wt[1][h].y = wgl[(size_t)(504 + 4*h + 1) * G3 + jlb];
        wt[1][h].z = wgl[(size_t)(504 + 4*h + 2) * G3 + jlb];
        wt[1][h].w = wgl[(size_t)(504 + 4*h + 3) * G3 + jlb];
      }
    }
    if (kind) {   // local h state <- h0
#pragma unroll
      for (int q = 0; q < 8; ++q)
        hl[wv * 516 + lane + 64*q] =
            h0[((size_t)widx * B_N + b0 + wv) * H_N + lane + 64*q];
    }
    __syncthreads();

    const float* xsrc = (ph == 0) ? x : (y0 + (size_t)d * T_N * B_N * H_N);
    const float4* wqa = (const float4*)wlds + jla;
    const float4* wqb = (const float4*)wlds + jlb;
    const float*  h1  = hl + boct * 516;
    const float*  h2  = hl + (boct + 8) * 516;

    // GEMM + dots(ring) + stats(ring) for step ss (kind0: ax; kind1: ah)
    auto run_step = [&](int ss) {
      float acc[2][2][4] = {{{0.f,0.f,0.f,0.f},{0.f,0.f,0.f,0.f}},
                            {{0.f,0.f,0.f,0.f},{0.f,0.f,0.f,0.f}}};
      if (gw) {
        if (kind) {
#pragma unroll 3
          for (int k4 = 0; k4 < 126; ++k4) {
            float4 wa = wqa[k4 * 64];
            float4 wb = wqb[k4 * 64];
            float4 r1 = *(const float4*)(h1 + k4 * 4);
            float4 r2 = *(const float4*)(h2 + k4 * 4);
            FMA16(wa, wb, r1, r2);
          }
          {
            float4 r1a = *(const float4*)(h1 + 504);
            float4 r1b = *(const float4*)(h1 + 508);
            float4 r2a = *(const float4*)(h2 + 504);
            float4 r2b = *(const float4*)(h2 + 508);
            FMA16(wt[0][0], wt[1][0], r1a, r2a);
            FMA16(wt[0][1], wt[1][1], r1b, r2b);
          }
        } else {
          const int t = d ? (T_N - 1 - ss) : ss;
          const float* rp1 = xsrc + ((size_t)t * B_N + b0 + boct) * H_N;
          const float* rp2 = rp1 + 8 * H_N;
#pragma unroll 6
          for (int k4 = 0; k4 < 126; ++k4) {
            float4 wa = wqa[k4 * 64];
            float4 wb = wqb[k4 * 64];
            float4 r1 = *(const float4*)(rp1 + k4 * 4);
            float4 r2 = *(const float4*)(rp2 + k4 * 4);
            FMA16(wa, wb, r1, r2);
          }
          {
            float4 r1a = *(const float4*)(rp1 + 504);
            float4 r1b = *(const float4*)(rp1 + 508);
            float4 r2a = *(const float4*)(rp2 + 504);
            float4 r2b = *(const float4*)(rp2 + 508);
            FMA16(wt[0][0], wt[1][0], r1a, r2a);
            FMA16(wt[0][1], wt[1][1], r1b, r2b);
          }
        }
      }
      float* dd  = kind ? (ahd + (ss & 1) * DSLOT) : (axd + (ss % 3) * DSLOT);
      float* stp = stats + (ss & 3) * STSLOT;
      if (gw) {
        float ta1 = bva + (acc[0][0][0] + acc[0][0][1]) + (acc[0][0][2] + acc[0][0][3]);
        float ta2 = bva + (acc[0][1][0] + acc[0][1][1]) + (acc[0][1][2] + acc[0][1][3]);
        float tb1 = bvb + (acc[1][0][0] + acc[1][0][1]) + (acc[1][0][2] + acc[1][0][3]);
        float tb2 = bvb + (acc[1][1][0] + acc[1][1][1]) + (acc[1][1][2] + acc[1][1][3]);

        float* dr1 = dd + (size_t)(d * B_N + b0 + boct) * G3 + j0;
        float* dr2 = dr1 + (size_t)8 * G3;
        cstore(dr1 + jla, ta1);
        cstore(dr1 + jlb, tb1);
        cstore(dr2 + jla, ta2);
        cstore(dr2 + jlb, tb2);

        float s1a = ta1 + tb1, s2a = ta1 * ta1 + tb1 * tb1;   // b = b0+boct
        float s1b = ta2 + tb2, s2b = ta2 * ta2 + tb2 * tb2;   // b = b0+boct+8
        s1a += __shfl_xor(s1a, 1, 64); s2a += __shfl_xor(s2a, 1, 64);
        s1b += __shfl_xor(s1b, 1, 64); s2b += __shfl_xor(s2b, 1, 64);
        s1a += __shfl_xor(s1a, 2, 64); s2a += __shfl_xor(s2a, 2, 64);
        s1b += __shfl_xor(s1b, 2, 64); s2b += __shfl_xor(s2b, 2, 64);
        s1a += __shfl_xor(s1a, 4, 64); s2a += __shfl_xor(s2a, 4, 64);
        s1b += __shfl_xor(s1b, 4, 64); s2b += __shfl_xor(s2b, 4, 64);
        if (jj == 0) {
          sred[(boct * 4 + jq) * 2 + 0] = s1a;
          sred[(boct * 4 + jq) * 2 + 1] = s2a;
          sred[((boct + 8) * 4 + jq) * 2 + 0] = s1b;
          sred[((boct + 8) * 4 + jq) * 2 + 1] = s2b;
        }
      }
      __syncthreads();
      if (tid < 32) {
        int bl = tid >> 1, st = tid & 1;
        float a2 = 0.f;
#pragma unroll
        for (int q = 0; q < 4; ++q) a2 += sred[(bl * 4 + q) * 2 + st];
        atomicAdd(&stp[((kd * 3 + g) * B_N + b0 + bl) * 2 + st], a2);
      }
    };

    if (!kind) run_step(0);       // prologue: ax(0) -> slot 0, stats slot 0
    gbar(barbase, epoch, bid);

    for (int s = 0; s < T_N; ++s) {
      // pre-barrier window: kind1 -> ah(s); kind0 -> ax(s+1)
      if (kind) run_step(s);
      else if (s < T_N - 1) run_step(s + 1);

      if (bid == NBLK - 1) {      // zero stats slot (s+2)&3 (disjoint from s, s+1)
        float* so = stats + ((s + 2) & 3) * STSLOT;
        if (tid < 768) cstore(so + tid, 0.f);
      }

      gbar(barbase, epoch, bid);  // the ONLY barrier per step

      // post-barrier: every kind1 block computes gates(s) for its own b-half
      if (kind) {
        const int t  = d ? (T_N - 1 - s) : s;
        const int gb = b0 + wv;
        const float* axr = axd + (s % 3) * DSLOT + (size_t)(d * B_N + gb) * G3;
        const float* ahr = ahd + (s & 1) * DSLOT + (size_t)(d * B_N + gb) * G3;
        const float* stp = stats + (s & 3) * STSLOT;
        float mu[2][3], inv[2][3];
#pragma unroll
        for (int k2 = 0; k2 < 2; ++k2)
#pragma unroll
          for (int g2 = 0; g2 < 3; ++g2) {
            const float* sl = stp + (((d * 2 + k2) * 3 + g2) * B_N + gb) * 2;
            float m1 = cload(sl)     * (1.f / 512.f);
            float m2 = cload(sl + 1) * (1.f / 512.f);
            mu[k2][g2]  = m1;
            inv[k2][g2] = rsqrtf(m2 - m1 * m1 + EPS_LN);
          }
        const float* gxr = gx  + widx * G3;
        const float* bxr = bex + widx * G3;
        const float* ghr = gh  + widx * G3;
        const float* bhr = beh + widx * G3;
#pragma unroll 2
        for (int q = 0; q < 8; ++q) {
          const int c = lane + 64 * q;
          float ax0 = cload(axr + c);
          float ax1 = cload(axr + H_N + c);
          float ax2 = cload(axr + 2 * H_N + c);
          float ah0 = cload(ahr + c);
          float ah1 = cload(ahr + H_N + c);
          float ah2 = cload(ahr + 2 * H_N + c);
          float a00 = (ax0 - mu[0][0]) * inv[0][0] * gxr[c]         + bxr[c];
          float a01 = (ax1 - mu[0][1]) * inv[0][1] * gxr[H_N + c]   + bxr[H_N + c];
          float a02 = (ax2 - mu[0][2]) * inv[0][2] * gxr[2*H_N + c] + bxr[2*H_N + c];
          float a10 = (ah0 - mu[1][0]) * inv[1][0] * ghr[c]         + bhr[c];
          float a11 = (ah1 - mu[1][1]) * inv[1][1] * ghr[H_N + c]   + bhr[H_N + c];
          float a12 = (ah2 - mu[1][2]) * inv[1][2] * ghr[2*H_N + c] + bhr[2*H_N + c];
          float r = 1.f / (1.f + __expf(-(a00 + a10)));
          float z = 1.f / (1.f + __expf(-(a01 + a11)));
          float n = tanhf(a02 + r * a12);
          float* hp = hl + wv * 516 + c;
          float hnew = (1.f - z) * n + z * *hp;
          *hp = hnew;
          if (writer) {
            if (ph == 0)
              cstore(&y0[(((size_t)d * T_N + t) * B_N + gb) * H_N + c], hnew);
            else
              out[((size_t)t * B_N + gb) * 1024 + d * H_N + c] = hnew;
            if (s == T_N - 1)
              out[OUT_HID_OFF + ((size_t)widx * B_N + gb) * H_N + c] = hnew;
          }
        }
        __syncthreads();   // h(s) in hl ready for ah-GEMM(s+1)
      }
    }
  }
}

extern "C" void kernel_launch(void* const* d_in, const int* in_sizes, int n_in,
                              void* d_out, int out_size, void* d_ws, size_t ws_size,
                              hipStream_t stream) {
  const float* x    = (const float*)d_in[0];
  const float* h0   = (const float*)d_in[1];
  const float* Wx   = (const float*)d_in[2];
  const float* Wh   = (const float*)d_in[3];
  const float* bxp  = (const float*)d_in[4];
  const float* bhp  = (const float*)d_in[5];
  const float* gxp  = (const float*)d_in[6];
  const float* bexp = (const float*)d_in[7];
  const float* ghp  = (const float*)d_in[8];
  const float* behp = (const float*)d_in[9];
  float* out = (float*)d_out;
  float* ws  = (float*)d_ws;

  hipMemsetAsync(d_ws, 0, 16384, stream);   // flags + release + 4-slot stats ring

  hipFuncSetAttribute((const void*)lngru14,
                      hipFuncAttributeMaxDynamicSharedMemorySize, LDS_BYTES);

  void* args[] = {(void*)&x, (void*)&h0, (void*)&Wx, (void*)&Wh, (void*)&bxp, (void*)&bhp,
                  (void*)&gxp, (void*)&bexp, (void*)&ghp, (void*)&behp, (void*)&out, (void*)&ws};
  hipLaunchCooperativeKernel((void*)lngru14, dim3(NBLK), dim3(NT), args, LDS_BYTES, stream);
}